// Round 3
// baseline (3078.786 us; speedup 1.0000x reference)
//
#include <hip/hip_runtime.h>

#define TT     32
#define HW     4096           // 64*64
#define LROW   67             // 66 cols + 1 pad (odd stride: window reads 2-way max)
#define LPLANE (6 * LROW)     // 402 floats per cin plane
#define LTOT   (3 * LPLANE)   // 1206
#define NSTG   (3 * 6 * 66)   // 1188 staged slots per time plane

__device__ __forceinline__ float fsigmoid(float x) {
    return __builtin_amdgcn_rcpf(1.0f + __builtin_amdgcn_exp2f(x * -1.4426950408889634f));
}
__device__ __forceinline__ float ftanh(float x) {
    return 2.0f * __builtin_amdgcn_rcpf(1.0f + __builtin_amdgcn_exp2f(x * -2.8853900817779268f)) - 1.0f;
}

__global__ __launch_bounds__(256, 4) void convqrnn(
    const float* __restrict__ X,    // (4,3,32,64,64)
    const float* __restrict__ Wc,   // (256,3,2,3,3)
    const float* __restrict__ bc,   // (256)
    const float* __restrict__ Wci,  // (64,64,64)
    const float* __restrict__ Wcf,
    const float* __restrict__ Wco,
    float* __restrict__ out)        // (4,64,32,64,64)
{
    __shared__ float sx[LTOT];     // one time-plane halo tile, 3 cin
    __shared__ float gb[4 * 256];  // gate exchange [gate][pixel]

    const int tid = threadIdx.x;
    const int h0  = blockIdx.x * 4;   // 16 row-tiles of height 4, full width
    const int co  = blockIdx.y;
    const int b   = blockIdx.z;

    // gate-compute mapping: wave g -> gate g; lane owns 4 consecutive cols
    const int g  = tid >> 6;
    const int l  = tid & 63;
    const int r  = l >> 4;            // tile row 0..3
    const int c0 = (l & 15) * 4;      // col base 0,4,...,60

    // recurrence-owner mapping: pixel = tid (4 rows x 64 cols row-major)
    const int opix = (h0 + (tid >> 6)) * 64 + (tid & 63);

    const float wci = Wci[co * HW + opix];
    const float wcf = Wcf[co * HW + opix];
    const float wco = Wco[co * HW + opix];

    // conv weights for (gate g, cout co): 54 floats resident in VGPRs
    float wgt[54];
    {
        const float* __restrict__ wrow = Wc + (size_t)(g * 64 + co) * 54;
        #pragma unroll
        for (int j = 0; j < 54; ++j) wgt[j] = wrow[j];
    }
    const float bg = bc[g * 64 + co];

    // ---- t-invariant staging maps: 5 chunks of 256 cover 3 x 6 x 66 ----
    const float* __restrict__ Xb = X + (size_t)b * (3 * TT * HW);
    int  soff[5];
    int  goff[5];
    bool sv[5];
    #pragma unroll
    for (int k = 0; k < 5; ++k) {
        const int idx = tid + k * 256;
        const int ci  = idx / 396;            // 6*66
        const int rem = idx - ci * 396;
        const int y   = rem / 66;
        const int x   = rem - y * 66;
        const int gh  = h0 + y - 1;
        const int gw  = x - 1;
        sv[k]   = (idx < NSTG) & ((unsigned)gh < 64u) & ((unsigned)gw < 64u);
        soff[k] = ci * LPLANE + y * LROW + x;
        goff[k] = ci * (TT * HW) + gh * 64 + gw;   // garbage if !sv (never used)
    }

    // zero the whole tile once (borders stay zero forever; mask is t-invariant)
    #pragma unroll
    for (int k = 0; k < 5; ++k) {
        const int idx = tid + k * 256;
        if (idx < LTOT) sx[idx] = 0.0f;
    }
    __syncthreads();

    // prologue: stage plane t=0
    #pragma unroll
    for (int k = 0; k < 5; ++k) {
        if (sv[k]) sx[soff[k]] = Xb[goff[k]];
        goff[k] += HW;
    }

    float* __restrict__ outb = out + (size_t)(b * 64 + co) * (TT * HW);
    int ooff = opix;

    float cn0 = 0.f, cn1 = 0.f, cn2 = 0.f, cn3 = 0.f;  // dt=0 partial carry
    float C = 0.f;

    for (int t = 0; t < TT; ++t) {
        __syncthreads();   // staged plane t visible; prev gb reads done

        // window: 3 cin x 3 rows x 6 cols from LDS
        float win[3][3][6];
        #pragma unroll
        for (int ci = 0; ci < 3; ++ci)
            #pragma unroll
            for (int kh = 0; kh < 3; ++kh)
                #pragma unroll
                for (int j = 0; j < 6; ++j)
                    win[ci][kh][j] = sx[ci * LPLANE + (r + kh) * LROW + c0 + j];

        // prefetch next plane (VMEM overlaps the FMAs below)
        float stv[5];
        if (t + 1 < TT) {
            #pragma unroll
            for (int k = 0; k < 5; ++k) {
                if (sv[k]) stv[k] = Xb[goff[k]];
                goff[k] += HW;
            }
        }

        // conv: s1 = dt=1 taps on plane t; nn = dt=0 taps (used at t+1)
        float s10 = bg, s11 = bg, s12 = bg, s13 = bg;
        float n0 = 0.f, n1 = 0.f, n2 = 0.f, n3 = 0.f;
        #pragma unroll
        for (int ci = 0; ci < 3; ++ci)
            #pragma unroll
            for (int kh = 0; kh < 3; ++kh)
                #pragma unroll
                for (int kw = 0; kw < 3; ++kw) {
                    const float wp = wgt[ci * 18 +     kh * 3 + kw];
                    const float wc = wgt[ci * 18 + 9 + kh * 3 + kw];
                    s10 = fmaf(wc, win[ci][kh][kw + 0], s10);
                    s11 = fmaf(wc, win[ci][kh][kw + 1], s11);
                    s12 = fmaf(wc, win[ci][kh][kw + 2], s12);
                    s13 = fmaf(wc, win[ci][kh][kw + 3], s13);
                    n0  = fmaf(wp, win[ci][kh][kw + 0], n0);
                    n1  = fmaf(wp, win[ci][kh][kw + 1], n1);
                    n2  = fmaf(wp, win[ci][kh][kw + 2], n2);
                    n3  = fmaf(wp, win[ci][kh][kw + 3], n3);
                }

        // gate exchange: 4 scalar b32 writes (2-way bank aliasing = free)
        const int gbase = g * 256 + r * 64 + c0;
        gb[gbase + 0] = s10 + cn0;
        gb[gbase + 1] = s11 + cn1;
        gb[gbase + 2] = s12 + cn2;
        gb[gbase + 3] = s13 + cn3;
        cn0 = n0; cn1 = n1; cn2 = n2; cn3 = n3;

        __syncthreads();   // gates visible; window reads of plane t done

        // recurrence (one pixel per thread)
        const float iv = gb[tid];
        const float fv = gb[256 + tid];
        const float gg = gb[512 + tid];
        const float ov = gb[768 + tid];
        const float ig = fsigmoid(iv + wci * C);
        const float fg = fsigmoid(fv + wcf * C);
        const float Cn = fg * C + ig * ftanh(gg);
        const float og = fsigmoid(ov + wco * Cn);
        outb[ooff] = og * ftanh(Cn);
        ooff += HW;
        C = Cn;

        // commit staged plane t+1 (made visible by next top-of-loop barrier)
        if (t + 1 < TT) {
            #pragma unroll
            for (int k = 0; k < 5; ++k)
                if (sv[k]) sx[soff[k]] = stv[k];
        }
    }
}

extern "C" void kernel_launch(void* const* d_in, const int* in_sizes, int n_in,
                              void* d_out, int out_size, void* d_ws, size_t ws_size,
                              hipStream_t stream) {
    const float* X   = (const float*)d_in[0];
    const float* Wc  = (const float*)d_in[1];
    const float* bc  = (const float*)d_in[2];
    const float* Wci = (const float*)d_in[3];
    const float* Wcf = (const float*)d_in[4];
    const float* Wco = (const float*)d_in[5];
    float* out = (float*)d_out;

    dim3 grid(16, 64, 4);   // row-tiles, cout, batch
    convqrnn<<<grid, 256, 0, stream>>>(X, Wc, bc, Wci, Wcf, Wco, out);
}

// Round 4
// 1607.629 us; speedup vs baseline: 1.9151x; 1.9151x over previous
//
#include <hip/hip_runtime.h>

#define TT      32
#define HW      4096            // 64*64
#define LROW    67              // 66 cols + 1 pad (odd stride -> conflict-free windows)
#define LPLANE  (6 * LROW)      // 402 floats per cin plane
#define LTOT    (3 * LPLANE)    // 1206
#define NSTG    (3 * 6 * 66)    // 1188 staged slots per time plane
#define GSTRIDE 268             // per-gate stride: 4 rows x 67 (padded vs 64!)
#define GTOT    (4 * GSTRIDE)   // 1072

__device__ __forceinline__ float fsigmoid(float x) {
    return __builtin_amdgcn_rcpf(1.0f + __builtin_amdgcn_exp2f(x * -1.4426950408889634f));
}
__device__ __forceinline__ float ftanh(float x) {
    return 2.0f * __builtin_amdgcn_rcpf(1.0f + __builtin_amdgcn_exp2f(x * -2.8853900817779268f)) - 1.0f;
}

__global__ __launch_bounds__(256, 2) void convqrnn(
    const float* __restrict__ X,    // (4,3,32,64,64)
    const float* __restrict__ Wc,   // (256,3,2,3,3)
    const float* __restrict__ bc,   // (256)
    const float* __restrict__ Wci,  // (64,64,64)
    const float* __restrict__ Wcf,
    const float* __restrict__ Wco,
    float* __restrict__ out)        // (4,64,32,64,64)
{
    __shared__ float sxa[LTOT], sxb[LTOT];   // double-buffered halo planes
    __shared__ float gba[GTOT], gbb[GTOT];   // double-buffered gate exchange

    const int tid = threadIdx.x;
    const int h0  = blockIdx.x * 4;   // 16 row-tiles of height 4, full width
    const int co  = blockIdx.y;
    const int b   = blockIdx.z;

    // gate-compute mapping: wave g -> gate g; lane owns 4 consecutive cols
    const int g  = tid >> 6;
    const int l  = tid & 63;
    const int r  = l >> 4;            // tile row 0..3
    const int c0 = (l & 15) * 4;      // col base 0,4,...,60

    // recurrence-owner mapping: pixel = tid (4 rows x 64 cols row-major)
    const int prow = tid >> 6;        // == wave id -> consecutive gb reads
    const int pcol = tid & 63;
    const int opix = (h0 + prow) * 64 + pcol;

    const float wci = Wci[co * HW + opix];
    const float wcf = Wcf[co * HW + opix];
    const float wco = Wco[co * HW + opix];

    // conv weights for (gate g, cout co): 54 floats resident in VGPRs
    float wgt[54];
    {
        const float* __restrict__ wrow = Wc + (size_t)(g * 64 + co) * 54;
        #pragma unroll
        for (int j = 0; j < 54; ++j) wgt[j] = wrow[j];
    }
    const float bg = bc[g * 64 + co];

    // t-invariant staging maps: 5 chunks of 256 cover 3 x 6 x 66
    const float* __restrict__ Xb = X + (size_t)b * (3 * TT * HW);
    int  soff[5];
    int  goff[5];
    bool sv[5];
    #pragma unroll
    for (int k = 0; k < 5; ++k) {
        const int idx = tid + k * 256;
        const int ci  = idx / 396;            // 6*66
        const int rem = idx - ci * 396;
        const int y   = rem / 66;
        const int x   = rem - y * 66;
        const int gh  = h0 + y - 1;
        const int gw  = x - 1;
        sv[k]   = (idx < NSTG) & ((unsigned)gh < 64u) & ((unsigned)gw < 64u);
        soff[k] = ci * LPLANE + y * LROW + x;
        goff[k] = ci * (TT * HW) + gh * 64 + gw;   // garbage if !sv (never read)
    }

    // zero both plane buffers once (borders stay zero; mask is t-invariant)
    #pragma unroll
    for (int k = 0; k < 5; ++k) {
        const int idx = tid + k * 256;
        if (idx < LTOT) { sxa[idx] = 0.0f; sxb[idx] = 0.0f; }
    }
    __syncthreads();

    // prologue: stage plane t=0 into sxa
    #pragma unroll
    for (int k = 0; k < 5; ++k) {
        if (sv[k]) sxa[soff[k]] = Xb[goff[k]];
        goff[k] += HW;
    }
    __syncthreads();

    float* __restrict__ outb = out + (size_t)(b * 64 + co) * (TT * HW);
    int ooff = opix;

    float cn0 = 0.f, cn1 = 0.f, cn2 = 0.f, cn3 = 0.f;  // dt=0 partial carry
    float C = 0.f;

    // one timestep: read plane from sxr, stage plane t+1 into sxw,
    // exchange gates through gbp; exactly ONE barrier per step.
    auto body = [&](int t, const float* __restrict__ sxr,
                    float* __restrict__ sxw, float* __restrict__ gbp) {
        // window: 3 cin x 3 rows x 6 cols (conflict-free: LROW=67)
        float win[3][3][6];
        #pragma unroll
        for (int ci = 0; ci < 3; ++ci)
            #pragma unroll
            for (int kh = 0; kh < 3; ++kh)
                #pragma unroll
                for (int j = 0; j < 6; ++j)
                    win[ci][kh][j] = sxr[ci * LPLANE + (r + kh) * LROW + c0 + j];

        // prefetch plane t+1 (VMEM overlaps FMAs)
        const bool live = (t + 1 < TT);
        float stv[5];
        #pragma unroll
        for (int k = 0; k < 5; ++k) {
            if (sv[k] & live) stv[k] = Xb[goff[k]];
            goff[k] += HW;
        }

        // conv: s1* = dt=1 taps on plane t; n* = dt=0 taps (used at t+1)
        float s10 = bg, s11 = bg, s12 = bg, s13 = bg;
        float n0 = 0.f, n1 = 0.f, n2 = 0.f, n3 = 0.f;
        #pragma unroll
        for (int ci = 0; ci < 3; ++ci)
            #pragma unroll
            for (int kh = 0; kh < 3; ++kh)
                #pragma unroll
                for (int kw = 0; kw < 3; ++kw) {
                    const float wp = wgt[ci * 18 +     kh * 3 + kw];
                    const float wc = wgt[ci * 18 + 9 + kh * 3 + kw];
                    s10 = fmaf(wc, win[ci][kh][kw + 0], s10);
                    s11 = fmaf(wc, win[ci][kh][kw + 1], s11);
                    s12 = fmaf(wc, win[ci][kh][kw + 2], s12);
                    s13 = fmaf(wc, win[ci][kh][kw + 3], s13);
                    n0  = fmaf(wp, win[ci][kh][kw + 0], n0);
                    n1  = fmaf(wp, win[ci][kh][kw + 1], n1);
                    n2  = fmaf(wp, win[ci][kh][kw + 2], n2);
                    n3  = fmaf(wp, win[ci][kh][kw + 3], n3);
                }

        // gate exchange: padded stride 67 -> 2-way bank aliasing (free)
        const int gbase = g * GSTRIDE + r * LROW + c0;
        gbp[gbase + 0] = s10 + cn0;
        gbp[gbase + 1] = s11 + cn1;
        gbp[gbase + 2] = s12 + cn2;
        gbp[gbase + 3] = s13 + cn3;
        cn0 = n0; cn1 = n1; cn2 = n2; cn3 = n3;

        // commit plane t+1 into the OTHER buffer (no reader this step)
        if (live) {
            #pragma unroll
            for (int k = 0; k < 5; ++k)
                if (sv[k]) sxw[soff[k]] = stv[k];
        }

        __syncthreads();   // gates + next plane visible

        // recurrence (one pixel per thread; gb reads consecutive -> free)
        const int rbase = prow * LROW + pcol;
        const float iv = gbp[0 * GSTRIDE + rbase];
        const float fv = gbp[1 * GSTRIDE + rbase];
        const float gg = gbp[2 * GSTRIDE + rbase];
        const float ov = gbp[3 * GSTRIDE + rbase];
        const float ig = fsigmoid(iv + wci * C);
        const float fg = fsigmoid(fv + wcf * C);
        const float Cn = fg * C + ig * ftanh(gg);
        const float og = fsigmoid(ov + wco * Cn);
        outb[ooff] = og * ftanh(Cn);
        ooff += HW;
        C = Cn;
    };

    for (int t = 0; t < TT; t += 2) {
        body(t,     sxa, sxb, gba);
        body(t + 1, sxb, sxa, gbb);
    }
}

extern "C" void kernel_launch(void* const* d_in, const int* in_sizes, int n_in,
                              void* d_out, int out_size, void* d_ws, size_t ws_size,
                              hipStream_t stream) {
    const float* X   = (const float*)d_in[0];
    const float* Wc  = (const float*)d_in[1];
    const float* bc  = (const float*)d_in[2];
    const float* Wci = (const float*)d_in[3];
    const float* Wcf = (const float*)d_in[4];
    const float* Wco = (const float*)d_in[5];
    float* out = (float*)d_out;

    dim3 grid(16, 64, 4);   // row-tiles, cout, batch
    convqrnn<<<grid, 256, 0, stream>>>(X, Wc, bc, Wci, Wcf, Wco, out);
}